// Round 3
// baseline (1140.888 us; speedup 1.0000x reference)
//
#include <hip/hip_runtime.h>

typedef float v4f __attribute__((ext_vector_type(4)));

// Problem constants (from reference)
constexpr int B = 256;        // batch
constexpr int T = 64;         // trees
constexpr int C = 1000;       // mask columns (idx domain)
constexpr int F = 16080;      // output feature width
constexpr int K = 200;        // top-k
constexpr int F4 = F / 4;     // 4020 float4 per row
constexpr int C4 = C / 4;     // 250 float4 with possible nonzeros
constexpr unsigned ND = (unsigned)B * T * C4;           // 4,096,000 dense quads
constexpr unsigned NZ = (unsigned)(B * T + T) * F4;     // 66,120,960 quads: return_value + attention

// Kernel 0: pure zero store stream over BOTH outputs (1.058 GB).
// Round-2 result: plain cached dwordx4 stores cap at ~2.6-3.1 TB/s (three
// different implementations), while rocclr fill hits 6.2 TB/s. Round-3 theory:
// cached stores write-allocate in L2 and the dirty-eviction engine throttles
// the stream. Fix: NON-TEMPORAL stores (global_store_dwordx4 nt) — coherent,
// but no L2 allocation/eviction churn.
__global__ __launch_bounds__(256) void zero_fill_kernel(v4f* __restrict__ p) {
  const v4f z = {0.0f, 0.0f, 0.0f, 0.0f};
  const unsigned stride = gridDim.x * 256u;
  for (unsigned i = blockIdx.x * 256u + threadIdx.x; i < NZ; i += stride)
    __builtin_nontemporal_store(z, &p[i]);
}

// Kernel 1: one block per tree. Find top-200 of the mask row via bitonic sort
// of packed keys in LDS, scatter sigmoid values into the (pre-zeroed) attn row.
// Key = (monotone(float_bits) << 32) | ~index  -> descending sort gives
// values descending, ties broken by lower index (matches lax.top_k).
__global__ __launch_bounds__(256) void topk_scatter_kernel(
    const float* __restrict__ mask, float* __restrict__ attn) {
  const int t = blockIdx.x;
  const int tid = threadIdx.x;
  __shared__ unsigned long long keys[1024];

  const float* row = mask + (size_t)t * C;

  // load + pack keys (pad to 1024 with key=0, sorts last in descending order)
  for (int i = tid; i < 1024; i += 256) {
    if (i < C) {
      unsigned ub = __float_as_uint(row[i]);
      unsigned mono = (ub & 0x80000000u) ? ~ub : (ub | 0x80000000u);
      keys[i] = ((unsigned long long)mono << 32) | (unsigned)(~i);
    } else {
      keys[i] = 0ull;
    }
  }
  __syncthreads();

  // bitonic sort, descending
  for (int k = 2; k <= 1024; k <<= 1) {
    for (int j = k >> 1; j > 0; j >>= 1) {
      for (int ii = tid; ii < 1024; ii += 256) {
        int l = ii ^ j;
        if (l > ii) {
          unsigned long long a = keys[ii];
          unsigned long long b2 = keys[l];
          bool sw = ((ii & k) == 0) ? (a < b2) : (a > b2);
          if (sw) { keys[ii] = b2; keys[l] = a; }
        }
      }
      __syncthreads();
    }
  }

  // scatter top-200: attn[t, idx] = sigmoid(value)
  if (tid < K) {
    unsigned long long key = keys[tid];
    unsigned idx = ~(unsigned)(key & 0xFFFFFFFFull);
    unsigned mono = (unsigned)(key >> 32);
    unsigned bits = (mono & 0x80000000u) ? (mono ^ 0x80000000u) : ~mono;
    float v = __uint_as_float(bits);
    float s = 1.0f / (1.0f + expf(-v));
    attn[(size_t)t * F + idx] = s;
  }
}

// Kernel 2: write ONLY the nonzero region — cols [0,1000) of every (b,t) row.
// 65.5 MB of stores (overwrites zeros from kernel 0); reads are L2-resident
// (x live set 1 MB, attn 256 KB).
__global__ __launch_bounds__(256) void dense_kernel(
    const float* __restrict__ x, const float* __restrict__ attn,
    float* __restrict__ out) {
  const v4f* __restrict__ x4 = (const v4f*)x;
  const v4f* __restrict__ a4 = (const v4f*)attn;
  v4f* __restrict__ o4 = (v4f*)out;

  const unsigned stride = gridDim.x * 256u;
  for (unsigned j = blockIdx.x * 256u + threadIdx.x; j < ND; j += stride) {
    unsigned row = j / (unsigned)C4;        // compiler magic-mul
    unsigned c = j - row * (unsigned)C4;    // quad col in [0,250)
    unsigned b = row >> 6;
    unsigned t = row & 63u;
    o4[(size_t)row * F4 + c] = x4[b * (unsigned)F4 + c] * a4[t * (unsigned)F4 + c];
  }
}

extern "C" void kernel_launch(void* const* d_in, const int* in_sizes, int n_in,
                              void* d_out, int out_size, void* d_ws, size_t ws_size,
                              hipStream_t stream) {
  const float* x = (const float*)d_in[0];          // (256,120,134) -> (256,16080)
  const float* mask = (const float*)d_in[1];       // (64,1000)
  float* out = (float*)d_out;                      // return_value (256,64,16080)
  float* attn = out + (size_t)B * T * F;           // attention (64,16080), 2nd output

  // 1) bulk-zero both outputs, non-temporal store stream (~31.5 iters/thread)
  zero_fill_kernel<<<8192, 256, 0, stream>>>((v4f*)d_out);

  // 2) top-k + sigmoid scatter into attention rows (after zero; same stream)
  topk_scatter_kernel<<<T, 256, 0, stream>>>(mask, attn);

  // 3) dense nonzero region: 4,096,000 float4s, ~8 per thread
  dense_kernel<<<2048, 256, 0, stream>>>(x, attn, out);
}

// Round 5
// 1090.121 us; speedup vs baseline: 1.0466x; 1.0466x over previous
//
#include <hip/hip_runtime.h>

typedef float v4f __attribute__((ext_vector_type(4)));

// Problem constants (from reference)
constexpr int B = 256;        // batch
constexpr int T = 64;         // trees
constexpr int C = 1000;       // mask columns (idx domain)
constexpr int F = 16080;      // output feature width
constexpr int K = 200;        // top-k
constexpr int F4 = F / 4;     // 4020 float4 per row
constexpr int C4 = C / 4;     // 250 float4 with possible nonzeros
constexpr unsigned ND = (unsigned)B * T * C4;            // 4,096,000 dense quads
constexpr unsigned NQ_RV = (unsigned)B * T * (unsigned)F4; // 65,863,680 quads (return_value)
constexpr int ZBLOCKS = 8192;
constexpr unsigned CHUNK = NQ_RV / (unsigned)ZBLOCKS;    // 8040 quads = 128,640 B (exact)

// Kernel 0: zero return_value with a CONTIGUOUS-chunk sweep.
// r0/r2/r3 lesson: grid-stride interleaved store streams cap at ~2.7-3.1 TB/s
// regardless of cache flags, while the runtime's fill (contiguous per-block
// work) hits 6.2 TB/s on the same buffer. This round tests address-space
// compactness: block h owns one contiguous 128.6 KB chunk, and the chunk
// mapping is XCD-contiguous (default round-robin h%8 = XCD; chunk index
// (h&7)*1024 + h>>3 gives each XCD one contiguous 132 MB span). Bijective:
// 8192 = 8 * 1024. Wave-coalesced inner loop (lane i -> quad base+i).
__global__ __launch_bounds__(256) void zero_sweep_kernel(v4f* __restrict__ p) {
  const unsigned h = blockIdx.x;
  const unsigned chunk = ((h & 7u) << 10) | (h >> 3);
  const v4f z = {0.0f, 0.0f, 0.0f, 0.0f};
  v4f* __restrict__ base = p + (size_t)chunk * CHUNK;
  for (unsigned j = threadIdx.x; j < CHUNK; j += 256u)
    base[j] = z;
}

// Kernel 1: one block per tree. Zero the attention row (4 MB total, the big
// sweep no longer covers it), find top-200 of the mask row via bitonic sort
// of packed keys in LDS, scatter sigmoid values.
// Key = (monotone(float_bits) << 32) | ~index  -> descending sort gives
// values descending, ties broken by lower index (matches lax.top_k).
__global__ __launch_bounds__(256) void topk_scatter_kernel(
    const float* __restrict__ mask, float* __restrict__ attn) {
  const int t = blockIdx.x;
  const int tid = threadIdx.x;
  __shared__ unsigned long long keys[1024];

  const float* row = mask + (size_t)t * C;
  float* arow = attn + (size_t)t * F;

  // load + pack keys (pad to 1024 with key=0, sorts last in descending order)
  for (int i = tid; i < 1024; i += 256) {
    if (i < C) {
      unsigned ub = __float_as_uint(row[i]);
      unsigned mono = (ub & 0x80000000u) ? ~ub : (ub | 0x80000000u);
      keys[i] = ((unsigned long long)mono << 32) | (unsigned)(~i);
    } else {
      keys[i] = 0ull;
    }
  }
  // zero the attention output row (vectorized) while keys land
  {
    v4f* arow4 = (v4f*)arow;
    const v4f z = {0.0f, 0.0f, 0.0f, 0.0f};
    for (int i = tid; i < F4; i += 256) arow4[i] = z;
  }
  __syncthreads();

  // bitonic sort, descending
  for (int k = 2; k <= 1024; k <<= 1) {
    for (int j = k >> 1; j > 0; j >>= 1) {
      for (int ii = tid; ii < 1024; ii += 256) {
        int l = ii ^ j;
        if (l > ii) {
          unsigned long long a = keys[ii];
          unsigned long long b2 = keys[l];
          bool sw = ((ii & k) == 0) ? (a < b2) : (a > b2);
          if (sw) { keys[ii] = b2; keys[l] = a; }
        }
      }
      __syncthreads();
    }
  }

  // scatter top-200: attn[t, idx] = sigmoid(value)
  if (tid < K) {
    unsigned long long key = keys[tid];
    unsigned idx = ~(unsigned)(key & 0xFFFFFFFFull);
    unsigned mono = (unsigned)(key >> 32);
    unsigned bits = (mono & 0x80000000u) ? (mono ^ 0x80000000u) : ~mono;
    float v = __uint_as_float(bits);
    float s = 1.0f / (1.0f + expf(-v));
    arow[idx] = s;
  }
}

// Kernel 2: write ONLY the nonzero region — cols [0,1000) of every (b,t) row.
// 65.5 MB of stores (overwrites zeros from kernel 0); reads are L2-resident
// (x live set 16.5 MB, attn 4 MB).
__global__ __launch_bounds__(256) void dense_kernel(
    const float* __restrict__ x, const float* __restrict__ attn,
    float* __restrict__ out) {
  const v4f* __restrict__ x4 = (const v4f*)x;
  const v4f* __restrict__ a4 = (const v4f*)attn;
  v4f* __restrict__ o4 = (v4f*)out;

  const unsigned stride = gridDim.x * 256u;
  for (unsigned j = blockIdx.x * 256u + threadIdx.x; j < ND; j += stride) {
    unsigned row = j / (unsigned)C4;        // compiler magic-mul
    unsigned c = j - row * (unsigned)C4;    // quad col in [0,250)
    unsigned b = row >> 6;
    unsigned t = row & 63u;
    o4[(size_t)row * F4 + c] = x4[b * (unsigned)F4 + c] * a4[t * (unsigned)F4 + c];
  }
}

extern "C" void kernel_launch(void* const* d_in, const int* in_sizes, int n_in,
                              void* d_out, int out_size, void* d_ws, size_t ws_size,
                              hipStream_t stream) {
  const float* x = (const float*)d_in[0];          // (256,120,134) -> (256,16080)
  const float* mask = (const float*)d_in[1];       // (64,1000)
  float* out = (float*)d_out;                      // return_value (256,64,16080)
  float* attn = out + (size_t)B * T * F;           // attention (64,16080), 2nd output

  // 1) zero return_value: contiguous per-block chunks, XCD-contiguous mapping
  zero_sweep_kernel<<<ZBLOCKS, 256, 0, stream>>>((v4f*)out);

  // 2) top-k + sigmoid scatter (also zeroes its own attn rows)
  topk_scatter_kernel<<<T, 256, 0, stream>>>(mask, attn);

  // 3) dense nonzero region: 4,096,000 float4s, ~8 per thread
  dense_kernel<<<2048, 256, 0, stream>>>(x, attn, out);
}

// Round 6
// 1069.151 us; speedup vs baseline: 1.0671x; 1.0196x over previous
//
#include <hip/hip_runtime.h>

typedef float v4f __attribute__((ext_vector_type(4)));

// Problem constants (from reference)
constexpr int B = 256;        // batch
constexpr int T = 64;         // trees
constexpr int C = 1000;       // mask columns (idx domain)
constexpr int F = 16080;      // output feature width
constexpr int K = 200;        // top-k
constexpr int F4 = F / 4;     // 4020 float4 per row
constexpr int C4 = C / 4;     // 250 float4 with possible nonzeros
constexpr unsigned ND = (unsigned)B * T * C4;  // 4,096,000 dense (nonzero-region) quads

// ===== Round-6 note (revert to round-1 structure, best measured: 1065.6 µs) ====
// Session evidence on the 1.06 GB zero/product store stream:
//   memset node ~3.2 TB/s | contiguous-chunk kernel ~2.9 | branchy sweep ~2.9 |
//   plain grid-stride stores ~2.6 | nt stores ~2.5
// Five independent implementations converge to 2.6-3.2 TB/s; cache policy,
// NT hints, and XCD-contiguous compact chunks each move <= +-20%. The rocclr
// fill's apparent 6.2 TB/s rests on a WRITE_SIZE that is exactly 4.00x the
// output size (likely counter inflation; m13's 6.29 TB/s float4 copy counted
// R+W => ~3.1 TB/s write-half). Conclusion: ~3.2 TB/s is the real pure-store
// ceiling here and the graph memset node is AT it. Keep r1 structure.

// Kernel 1: one block per tree. Find top-200 of the mask row via bitonic sort
// of packed keys in LDS, scatter sigmoid values into the (pre-zeroed) attn row.
// Key = (monotone(float_bits) << 32) | ~index  -> descending sort gives
// values descending, ties broken by lower index (matches lax.top_k).
// NOTE: attention row zeroing is handled by the bulk hipMemsetAsync.
__global__ __launch_bounds__(256) void topk_scatter_kernel(
    const float* __restrict__ mask, float* __restrict__ attn) {
  const int t = blockIdx.x;
  const int tid = threadIdx.x;
  __shared__ unsigned long long keys[1024];

  const float* row = mask + (size_t)t * C;

  // load + pack keys (pad to 1024 with key=0, sorts last in descending order)
  for (int i = tid; i < 1024; i += 256) {
    if (i < C) {
      unsigned ub = __float_as_uint(row[i]);
      unsigned mono = (ub & 0x80000000u) ? ~ub : (ub | 0x80000000u);
      keys[i] = ((unsigned long long)mono << 32) | (unsigned)(~i);
    } else {
      keys[i] = 0ull;
    }
  }
  __syncthreads();

  // bitonic sort, descending
  for (int k = 2; k <= 1024; k <<= 1) {
    for (int j = k >> 1; j > 0; j >>= 1) {
      for (int ii = tid; ii < 1024; ii += 256) {
        int l = ii ^ j;
        if (l > ii) {
          unsigned long long a = keys[ii];
          unsigned long long b2 = keys[l];
          bool sw = ((ii & k) == 0) ? (a < b2) : (a > b2);
          if (sw) { keys[ii] = b2; keys[l] = a; }
        }
      }
      __syncthreads();
    }
  }

  // scatter top-200: attn[t, idx] = sigmoid(value)
  if (tid < K) {
    unsigned long long key = keys[tid];
    unsigned idx = ~(unsigned)(key & 0xFFFFFFFFull);
    unsigned mono = (unsigned)(key >> 32);
    unsigned bits = (mono & 0x80000000u) ? (mono ^ 0x80000000u) : ~mono;
    float v = __uint_as_float(bits);
    float s = 1.0f / (1.0f + expf(-v));
    attn[(size_t)t * F + idx] = s;
  }
}

// Kernel 2: write ONLY the nonzero region — cols [0,1000) of every (b,t) row.
// 65.5 MB of stores (overwrites zeros from the memset); reads are L2/L3-
// resident (x live set 1 MB, attn 256 KB).
__global__ __launch_bounds__(256) void dense_kernel(
    const float* __restrict__ x, const float* __restrict__ attn,
    float* __restrict__ out) {
  const v4f* __restrict__ x4 = (const v4f*)x;
  const v4f* __restrict__ a4 = (const v4f*)attn;
  v4f* __restrict__ o4 = (v4f*)out;

  const unsigned stride = gridDim.x * 256u;
  for (unsigned j = blockIdx.x * 256u + threadIdx.x; j < ND; j += stride) {
    unsigned row = j / (unsigned)C4;        // compiler magic-mul
    unsigned c = j - row * (unsigned)C4;    // quad col in [0,250)
    unsigned b = row >> 6;
    unsigned t = row & 63u;
    o4[(size_t)row * F4 + c] = x4[b * (unsigned)F4 + c] * a4[t * (unsigned)F4 + c];
  }
}

extern "C" void kernel_launch(void* const* d_in, const int* in_sizes, int n_in,
                              void* d_out, int out_size, void* d_ws, size_t ws_size,
                              hipStream_t stream) {
  const float* x = (const float*)d_in[0];          // (256,120,134) -> (256,16080)
  const float* mask = (const float*)d_in[1];       // (64,1000)
  float* out = (float*)d_out;                      // return_value (256,64,16080)
  float* attn = out + (size_t)B * T * F;           // attention (64,16080), 2nd output

  // 1) bulk-zero both outputs (graph memset node, ~3.2 TB/s = measured ceiling)
  const size_t total_bytes = ((size_t)B * T + (size_t)T) * (size_t)F * sizeof(float);
  hipMemsetAsync(d_out, 0, total_bytes, stream);

  // 2) top-k + sigmoid scatter into attention rows (depends on memset; same stream)
  topk_scatter_kernel<<<T, 256, 0, stream>>>(mask, attn);

  // 3) dense nonzero region: 4,096,000 float4s, ~8 per thread
  dense_kernel<<<2048, 256, 0, stream>>>(x, attn, out);
}